// Round 16
// baseline (697.122 us; speedup 1.0000x reference)
//
#include <hip/hip_runtime.h>
#include <hip/hip_cooperative_groups.h>
#include <cstddef>

namespace cg = cooperative_groups;

#define TT 64
#define RFL(x) __builtin_amdgcn_readfirstlane(x)

typedef unsigned long long u64;

// ---- workspace layout (floats from ws base); shared by mega + fallback ----
#define OFF_W1T   0
#define OFF_W2T   400
#define OFF_W3T   6800
#define OFF_WD1   58000
#define OFF_WD2P  584336
#define OFF_Z4P   609008
#define OFF_S3    789232
#define OFF_S4    1051376
#define OFF_S2    3156720
#define OFF_XB    5253872
#define OFF_S1B   6302448

// ---------------- CUBA LIF step helpers ----------------
__device__ __forceinline__ void scanc(float& c, float& v, float& z) {
    c = fmaf(0.7f, c, z);
    v = fmaf(0.75f, v, c);
    float s = (v >= 1.0f) ? 1.0f : 0.0f;
    v = (v >= 1.0f) ? 0.0f : v;
    z = s;
}
__device__ __forceinline__ void scan4(float& c, float& v, float4& a) {
    scanc(c, v, a.x); scanc(c, v, a.y); scanc(c, v, a.z); scanc(c, v, a.w);
}
__device__ __forceinline__ float bit2f(u64 m, int t) {
    return (float)((m >> t) & 1ULL);
}
__device__ __forceinline__ void scan_row(float* row) {
    float c = 0.f, v = 0.f;
    for (int tc = 0; tc < 4; tc++) {
        float4 r0 = *(const float4*)&row[tc * 16 + 0];
        float4 r1 = *(const float4*)&row[tc * 16 + 4];
        float4 r2 = *(const float4*)&row[tc * 16 + 8];
        float4 r3 = *(const float4*)&row[tc * 16 + 12];
        scan4(c, v, r0); scan4(c, v, r1); scan4(c, v, r2); scan4(c, v, r3);
        *(float4*)&row[tc * 16 + 0] = r0; *(float4*)&row[tc * 16 + 4] = r1;
        *(float4*)&row[tc * 16 + 8] = r2; *(float4*)&row[tc * 16 + 12] = r3;
    }
}

// ================= stage bodies (exact R12 arithmetic) ======================

__device__ __forceinline__ void st_prep(
    int bid, float* sm,
    const float* c1v, const float* c1g,
    const float* c2v, const float* c2g,
    const float* c3v, const float* c3g,
    const float* d1v, const float* d1g,
    const float* d2v, const float* d2g,
    const float* x, float* ws) {
    float* w1T  = ws + OFF_W1T;
    float* w2T  = ws + OFF_W2T;
    float* w3T  = ws + OFF_W3T;
    float* wd1  = ws + OFF_WD1;
    float* wd2P = ws + OFF_WD2P;
    u64* xb = (u64*)(ws + OFF_XB);
    if (bid >= 2171) {  // ---- pack path ----
        const int sub = threadIdx.x & 15;
        const int grp = threadIdx.x >> 4;
        const int pb = bid - 2171;  // 0..4095
#pragma unroll
        for (int it = 0; it < 4; it++) {
            const size_t base = ((size_t)pb * 4 + it) * 32;
            const size_t p0 = base + grp;
            const size_t p1 = base + 16 + grp;
            const float4 v0 = *(const float4*)(x + p0 * TT + sub * 4);
            const float4 v1 = *(const float4*)(x + p1 * TT + sub * 4);
            const unsigned int n0 = (v0.x > 0.5f ? 1u : 0u) | (v0.y > 0.5f ? 2u : 0u) |
                                    (v0.z > 0.5f ? 4u : 0u) | (v0.w > 0.5f ? 8u : 0u);
            const unsigned int n1 = (v1.x > 0.5f ? 1u : 0u) | (v1.y > 0.5f ? 2u : 0u) |
                                    (v1.z > 0.5f ? 4u : 0u) | (v1.w > 0.5f ? 8u : 0u);
            u64 w0 = (u64)n0 << (4 * sub);
            u64 w1 = (u64)n1 << (4 * sub);
            w0 |= __shfl_xor(w0, 1); w1 |= __shfl_xor(w1, 1);
            w0 |= __shfl_xor(w0, 2); w1 |= __shfl_xor(w1, 2);
            w0 |= __shfl_xor(w0, 4); w1 |= __shfl_xor(w1, 4);
            w0 |= __shfl_xor(w0, 8); w1 |= __shfl_xor(w1, 8);
            if (sub == 0) { xb[p0] = w0; xb[p1] = w1; }
        }
        return;
    }
    const float *v, *g; float* w; int o, K, LD; bool tr;
    if (bid < 8)         { v = c1v; g = c1g; w = w1T;  o = bid;        K = 50;   LD = 8;  tr = true;  }
    else if (bid < 40)   { v = c2v; g = c2g; w = w2T;  o = bid - 8;    K = 200;  LD = 32; tr = true;  }
    else if (bid < 104)  { v = c3v; g = c3g; w = w3T;  o = bid - 40;   K = 800;  LD = 64; tr = true;  }
    else if (bid < 2160) { v = d1v; g = d1g; w = wd1;  o = bid - 104;  K = 256;  LD = 0;  tr = false; }
    else                 { v = d2v; g = d2g; w = wd2P; o = bid - 2160; K = 2056; LD = 12; tr = true;  }

    float s = 0.f;
    for (int k = threadIdx.x; k < K; k += 256) {
        float xx = v[(size_t)o * K + k];
        s += xx * xx;
    }
    sm[threadIdx.x] = s;
    __syncthreads();
    for (int off = 128; off > 0; off >>= 1) {
        if (threadIdx.x < off) sm[threadIdx.x] += sm[threadIdx.x + off];
        __syncthreads();
    }
    const float scale = g[o] / sqrtf(sm[0]);
    __syncthreads();
    for (int k = threadIdx.x; k < K; k += 256) {
        float val = scale * v[(size_t)o * K + k];
        if (tr) w[(size_t)k * LD + o] = val;
        else    w[(size_t)o * K + k] = val;
    }
}

__device__ __forceinline__ void st_conv1(int task4, float* sm, float* ws) {
    const u64* xb = (const u64*)(ws + OFF_XB);
    const float* w1T = ws + OFF_W1T;
    u64* s1b = (u64*)(ws + OFF_S1B);
    const int wid = RFL(threadIdx.x >> 6), t = threadIdx.x & 63;
    const int task = task4 * 4 + wid;  // 0..16383
    const int spi = task & 1023, b = task >> 10;
    const int oy = spi >> 5, ox = spi & 31;

    float a0=0,a1=0,a2=0,a3=0,a4=0,a5=0,a6=0,a7=0;
    const u64* xq = xb + (size_t)b * 32768;

    if (oy >= 1 && ox >= 1) {
        const u64* xi = xq + (size_t)(oy * 4 - 1) * 128 + (ox * 4 - 1);
        for (int ci = 0; ci < 2; ci++) {
            u64 m[25];
#pragma unroll
            for (int ky = 0; ky < 5; ky++)
#pragma unroll
                for (int kx = 0; kx < 5; kx++)
                    m[ky * 5 + kx] = xi[ci * 16384 + ky * 128 + kx];
#pragma unroll
            for (int k = 0; k < 25; k++) {
                const float xvk = bit2f(m[k], t);
                const float4* wp = (const float4*)(w1T + (ci * 25 + k) * 8);
                const float4 wA = wp[0], wB = wp[1];
                a0 = fmaf(wA.x, xvk, a0); a1 = fmaf(wA.y, xvk, a1);
                a2 = fmaf(wA.z, xvk, a2); a3 = fmaf(wA.w, xvk, a3);
                a4 = fmaf(wB.x, xvk, a4); a5 = fmaf(wB.y, xvk, a5);
                a6 = fmaf(wB.z, xvk, a6); a7 = fmaf(wB.w, xvk, a7);
            }
        }
    } else {
        for (int ci = 0; ci < 2; ci++) {
#pragma unroll
            for (int ky = 0; ky < 5; ky++) {
                const int iy = oy * 4 + ky - 1;
                if (iy < 0 || iy >= 128) continue;
#pragma unroll
                for (int kx = 0; kx < 5; kx++) {
                    const int ix = ox * 4 + kx - 1;
                    if (ix < 0 || ix >= 128) continue;
                    const float xvk = bit2f(xq[ci * 16384 + iy * 128 + ix], t);
                    const float4* wp = (const float4*)(w1T + (ci * 25 + ky * 5 + kx) * 8);
                    const float4 wA = wp[0], wB = wp[1];
                    a0 = fmaf(wA.x, xvk, a0); a1 = fmaf(wA.y, xvk, a1);
                    a2 = fmaf(wA.z, xvk, a2); a3 = fmaf(wA.w, xvk, a3);
                    a4 = fmaf(wB.x, xvk, a4); a5 = fmaf(wB.y, xvk, a5);
                    a6 = fmaf(wB.z, xvk, a6); a7 = fmaf(wB.w, xvk, a7);
                }
            }
        }
    }
    float* rows = sm + wid * 8 * 68;
    rows[0 * 68 + t] = a0; rows[1 * 68 + t] = a1;
    rows[2 * 68 + t] = a2; rows[3 * 68 + t] = a3;
    rows[4 * 68 + t] = a4; rows[5 * 68 + t] = a5;
    rows[6 * 68 + t] = a6; rows[7 * 68 + t] = a7;
    __syncthreads();
    if (t < 8) scan_row(rows + t * 68);
    __syncthreads();
    u64* ob = s1b + (size_t)b * 8192 + spi;
#pragma unroll
    for (int ch = 0; ch < 8; ch++) {
        const u64 m = __ballot(rows[ch * 68 + t] > 0.5f);
        if (t == 0) ob[(size_t)ch * 1024] = m;
    }
    __syncthreads();
}

__device__ __forceinline__ void st_conv2(int u, float* sm, float* ws) {
    const u64* s1b = (const u64*)(ws + OFF_S1B);
    const float* w2T = ws + OFF_W2T;
    float* s2 = ws + OFF_S2;
    const int wid = RFL(threadIdx.x >> 6), t = threadIdx.x & 63;
    const int task = u * 4 + wid;  // 0..2047
    const int og = task & 1;
    const int spi = (task >> 1) & 63;
    const int b = task >> 7;
    const int oy = spi >> 3, ox = spi & 7;

    float a[16];
#pragma unroll
    for (int j = 0; j < 16; j++) a[j] = 0.f;
    const u64* sb = s1b + (size_t)b * 8192;

    if (oy >= 1 && ox >= 1) {
        const u64* si = sb + (size_t)(oy * 4 - 1) * 32 + (ox * 4 - 1);
        for (int ci = 0; ci < 8; ci++) {
            u64 m[25];
#pragma unroll
            for (int ky = 0; ky < 5; ky++)
#pragma unroll
                for (int kx = 0; kx < 5; kx++)
                    m[ky * 5 + kx] = si[ci * 1024 + ky * 32 + kx];
#pragma unroll
            for (int k = 0; k < 25; k++) {
                const float xvk = bit2f(m[k], t);
                const float4* wp = (const float4*)(w2T + (ci * 25 + k) * 32 + og * 16);
                const float4 w0 = wp[0], w1 = wp[1], w2 = wp[2], w3 = wp[3];
                a[0]  = fmaf(w0.x, xvk, a[0]);  a[1]  = fmaf(w0.y, xvk, a[1]);
                a[2]  = fmaf(w0.z, xvk, a[2]);  a[3]  = fmaf(w0.w, xvk, a[3]);
                a[4]  = fmaf(w1.x, xvk, a[4]);  a[5]  = fmaf(w1.y, xvk, a[5]);
                a[6]  = fmaf(w1.z, xvk, a[6]);  a[7]  = fmaf(w1.w, xvk, a[7]);
                a[8]  = fmaf(w2.x, xvk, a[8]);  a[9]  = fmaf(w2.y, xvk, a[9]);
                a[10] = fmaf(w2.z, xvk, a[10]); a[11] = fmaf(w2.w, xvk, a[11]);
                a[12] = fmaf(w3.x, xvk, a[12]); a[13] = fmaf(w3.y, xvk, a[13]);
                a[14] = fmaf(w3.z, xvk, a[14]); a[15] = fmaf(w3.w, xvk, a[15]);
            }
        }
    } else {
        for (int ci = 0; ci < 8; ci++) {
#pragma unroll
            for (int ky = 0; ky < 5; ky++) {
                const int iy = oy * 4 + ky - 1;
                if (iy < 0 || iy >= 32) continue;
#pragma unroll
                for (int kx = 0; kx < 5; kx++) {
                    const int ix = ox * 4 + kx - 1;
                    if (ix < 0 || ix >= 32) continue;
                    const float xvk = bit2f(sb[ci * 1024 + iy * 32 + ix], t);
                    const float4* wp =
                        (const float4*)(w2T + (ci * 25 + ky * 5 + kx) * 32 + og * 16);
                    const float4 w0 = wp[0], w1 = wp[1], w2 = wp[2], w3 = wp[3];
                    a[0]  = fmaf(w0.x, xvk, a[0]);  a[1]  = fmaf(w0.y, xvk, a[1]);
                    a[2]  = fmaf(w0.z, xvk, a[2]);  a[3]  = fmaf(w0.w, xvk, a[3]);
                    a[4]  = fmaf(w1.x, xvk, a[4]);  a[5]  = fmaf(w1.y, xvk, a[5]);
                    a[6]  = fmaf(w1.z, xvk, a[6]);  a[7]  = fmaf(w1.w, xvk, a[7]);
                    a[8]  = fmaf(w2.x, xvk, a[8]);  a[9]  = fmaf(w2.y, xvk, a[9]);
                    a[10] = fmaf(w2.z, xvk, a[10]); a[11] = fmaf(w2.w, xvk, a[11]);
                    a[12] = fmaf(w3.x, xvk, a[12]); a[13] = fmaf(w3.y, xvk, a[13]);
                    a[14] = fmaf(w3.z, xvk, a[14]); a[15] = fmaf(w3.w, xvk, a[15]);
                }
            }
        }
    }
    float* rows = sm + wid * 16 * 68;
#pragma unroll
    for (int j = 0; j < 16; j++) rows[j * 68 + t] = a[j];
    __syncthreads();
    if (t < 16) scan_row(rows + t * 68);
    __syncthreads();
    if (t < 16) {
        const float* row = rows + t * 68;
        float4* op = (float4*)(s2 + (((size_t)b * 32 + og * 16 + t) * 64 + spi) * TT);
#pragma unroll
        for (int q = 0; q < 16; q++) op[q] = *(const float4*)&row[q * 4];
    }
    __syncthreads();
}

__device__ __forceinline__ void st_conv3(int u, float* sm, float* ws) {
    const float* s2 = ws + OFF_S2;
    const float* wT = ws + OFF_W3T;
    float* s3 = ws + OFF_S3;
    const int wid = RFL(threadIdx.x >> 6), t = threadIdx.x & 63;
    const int og = u & 7;
    const int spi = (u >> 3) & 3;
    const int b = u >> 5;
    const int oy = spi >> 1, ox = spi & 1;
    const int ky0 = (oy == 0) ? 1 : 0;
    const int kx0 = (ox == 0) ? 1 : 0;

    float acc[8];
#pragma unroll
    for (int j = 0; j < 8; j++) acc[j] = 0.f;
    const float* xb = s2 + (size_t)b * 32 * 64 * TT + t;
    const float* wTo = wT + og * 8;

    for (int c8 = 0; c8 < 8; c8++) {
        const int ci = wid * 8 + c8;
        float xv[25];
        for (int ky = ky0; ky < 5; ky++)
            for (int kx = kx0; kx < 5; kx++) {
                const int iy = oy * 4 + ky - 1;
                const int ix = ox * 4 + kx - 1;
                xv[ky * 5 + kx] = xb[((size_t)((ci * 8 + iy) * 8 + ix)) * TT];
            }
        for (int ky = ky0; ky < 5; ky++)
            for (int kx = kx0; kx < 5; kx++) {
                const float xvk = xv[ky * 5 + kx];
                const float4* wp = (const float4*)(wTo + (ci * 25 + ky * 5 + kx) * 64);
                const float4 wA = wp[0], wB = wp[1];
                acc[0] = fmaf(wA.x, xvk, acc[0]); acc[1] = fmaf(wA.y, xvk, acc[1]);
                acc[2] = fmaf(wA.z, xvk, acc[2]); acc[3] = fmaf(wA.w, xvk, acc[3]);
                acc[4] = fmaf(wB.x, xvk, acc[4]); acc[5] = fmaf(wB.y, xvk, acc[5]);
                acc[6] = fmaf(wB.z, xvk, acc[6]); acc[7] = fmaf(wB.w, xvk, acc[7]);
            }
    }
#pragma unroll
    for (int j = 0; j < 8; j++) sm[(wid * 8 + j) * 68 + t] = acc[j];
    __syncthreads();
    if (wid == 0) {
#pragma unroll
        for (int j = 0; j < 8; j++)
            sm[j * 68 + t] = ((sm[j * 68 + t] + sm[(8 + j) * 68 + t]) +
                              sm[(16 + j) * 68 + t]) + sm[(24 + j) * 68 + t];
    }
    __syncthreads();
    if (threadIdx.x < 8) {
        const int j = threadIdx.x;
        float* row = sm + j * 68;
        scan_row(row);
        float4* op = (float4*)(s3 + ((size_t)b * 256 + og * 32 + j * 4 + spi) * TT);
#pragma unroll
        for (int q = 0; q < 16; q++) op[q] = *(const float4*)&row[q * 4];
    }
    __syncthreads();
}

__device__ __forceinline__ void st_dense1(int u, float* sm, float* ws) {
    const float* s3 = ws + OFF_S3;
    const float* w = ws + OFF_WD1;
    float* s4 = ws + OFF_S4;
    const int wid = threadIdx.x >> 6, t = threadIdx.x & 63;
    const int task = u * 4 + wid;  // 0..4111
    const int bq = task / 257;
    const int ogq = task - bq * 257;
    const int b = RFL(bq);
    const int o0 = RFL(ogq * 8);

    float a0=0,a1=0,a2=0,a3=0,a4=0,a5=0,a6=0,a7=0;
    const float* ab = s3 + (size_t)b * 256 * TT + t;
    const float* r0 = w + (size_t)(o0 + 0) * 256;
    const float* r1 = w + (size_t)(o0 + 1) * 256;
    const float* r2 = w + (size_t)(o0 + 2) * 256;
    const float* r3 = w + (size_t)(o0 + 3) * 256;
    const float* r4 = w + (size_t)(o0 + 4) * 256;
    const float* r5 = w + (size_t)(o0 + 5) * 256;
    const float* r6 = w + (size_t)(o0 + 6) * 256;
    const float* r7 = w + (size_t)(o0 + 7) * 256;

#pragma unroll 2
    for (int i = 0; i < 256; i += 4) {
        const float av0 = ab[(size_t)(i + 0) * TT];
        const float av1 = ab[(size_t)(i + 1) * TT];
        const float av2 = ab[(size_t)(i + 2) * TT];
        const float av3 = ab[(size_t)(i + 3) * TT];
        const float4 q0 = *(const float4*)(r0 + i);
        const float4 q1 = *(const float4*)(r1 + i);
        const float4 q2 = *(const float4*)(r2 + i);
        const float4 q3 = *(const float4*)(r3 + i);
        const float4 q4 = *(const float4*)(r4 + i);
        const float4 q5 = *(const float4*)(r5 + i);
        const float4 q6 = *(const float4*)(r6 + i);
        const float4 q7 = *(const float4*)(r7 + i);
        a0 = fmaf(q0.x, av0, a0); a1 = fmaf(q1.x, av0, a1);
        a2 = fmaf(q2.x, av0, a2); a3 = fmaf(q3.x, av0, a3);
        a4 = fmaf(q4.x, av0, a4); a5 = fmaf(q5.x, av0, a5);
        a6 = fmaf(q6.x, av0, a6); a7 = fmaf(q7.x, av0, a7);
        a0 = fmaf(q0.y, av1, a0); a1 = fmaf(q1.y, av1, a1);
        a2 = fmaf(q2.y, av1, a2); a3 = fmaf(q3.y, av1, a3);
        a4 = fmaf(q4.y, av1, a4); a5 = fmaf(q5.y, av1, a5);
        a6 = fmaf(q6.y, av1, a6); a7 = fmaf(q7.y, av1, a7);
        a0 = fmaf(q0.z, av2, a0); a1 = fmaf(q1.z, av2, a1);
        a2 = fmaf(q2.z, av2, a2); a3 = fmaf(q3.z, av2, a3);
        a4 = fmaf(q4.z, av2, a4); a5 = fmaf(q5.z, av2, a5);
        a6 = fmaf(q6.z, av2, a6); a7 = fmaf(q7.z, av2, a7);
        a0 = fmaf(q0.w, av3, a0); a1 = fmaf(q1.w, av3, a1);
        a2 = fmaf(q2.w, av3, a2); a3 = fmaf(q3.w, av3, a3);
        a4 = fmaf(q4.w, av3, a4); a5 = fmaf(q5.w, av3, a5);
        a6 = fmaf(q6.w, av3, a6); a7 = fmaf(q7.w, av3, a7);
    }
    float* rows = sm + wid * 8 * 68;
    rows[0 * 68 + t] = a0; rows[1 * 68 + t] = a1;
    rows[2 * 68 + t] = a2; rows[3 * 68 + t] = a3;
    rows[4 * 68 + t] = a4; rows[5 * 68 + t] = a5;
    rows[6 * 68 + t] = a6; rows[7 * 68 + t] = a7;
    __syncthreads();
    if (t < 8) {
        float* row = rows + t * 68;
        scan_row(row);
        float4* op = (float4*)(s4 + ((size_t)b * 2056 + o0 + t) * TT);
#pragma unroll
        for (int q = 0; q < 16; q++) op[q] = *(const float4*)&row[q * 4];
    }
    __syncthreads();
}

__device__ __forceinline__ void st_d2part(int u, float* sm, float* ws) {
    const float* s4 = ws + OFF_S4;
    const float* wP = ws + OFF_WD2P;
    float* z4p = ws + OFF_Z4P;
    const int sp = u % 16, b = u / 16;
    const int w = threadIdx.x >> 6, t = threadIdx.x & 63;
    const int i0 = sp * 129;
    const int iend = (i0 + 129 < 2056) ? i0 + 129 : 2056;
    const float* src = s4 + (size_t)b * 2056 * TT + t;

    float acc[11];
#pragma unroll
    for (int j = 0; j < 11; j++) acc[j] = 0.f;

#pragma unroll 4
    for (int i = i0 + w; i < iend; i += 4) {
        const float xv = src[(size_t)i * TT];
        const float4* wp = (const float4*)(wP + (size_t)i * 12);
        const float4 w0 = wp[0], w1 = wp[1], w2 = wp[2];
        acc[0]  = fmaf(w0.x, xv, acc[0]);  acc[1]  = fmaf(w0.y, xv, acc[1]);
        acc[2]  = fmaf(w0.z, xv, acc[2]);  acc[3]  = fmaf(w0.w, xv, acc[3]);
        acc[4]  = fmaf(w1.x, xv, acc[4]);  acc[5]  = fmaf(w1.y, xv, acc[5]);
        acc[6]  = fmaf(w1.z, xv, acc[6]);  acc[7]  = fmaf(w1.w, xv, acc[7]);
        acc[8]  = fmaf(w2.x, xv, acc[8]);  acc[9]  = fmaf(w2.y, xv, acc[9]);
        acc[10] = fmaf(w2.z, xv, acc[10]);
    }
#pragma unroll
    for (int j = 0; j < 11; j++) sm[(w * 11 + j) * 64 + t] = acc[j];
    __syncthreads();
    if (w == 0) {
#pragma unroll
        for (int j = 0; j < 11; j++) {
            const float s = sm[j * 64 + t] + sm[(11 + j) * 64 + t] +
                            sm[(22 + j) * 64 + t] + sm[(33 + j) * 64 + t];
            z4p[(((size_t)b * 16 + sp) * 11 + j) * TT + t] = s;
        }
    }
    __syncthreads();
}

__device__ __forceinline__ void st_d2scan(int b, float* sm, float* ws, float* out) {
    const float* z4p = ws + OFF_Z4P;
    for (int idx = threadIdx.x; idx < 11 * 64; idx += 256) {
        const int o = idx >> 6, t = idx & 63;
        float s = 0.f;
#pragma unroll
        for (int sp = 0; sp < 16; sp++)
            s += z4p[(((size_t)b * 16 + sp) * 11 + o) * TT + t];
        sm[o * 64 + t] = s;
    }
    __syncthreads();
    if (threadIdx.x < 11) {
        const int o = threadIdx.x;
        float c = 0.f, v = 0.f;
        float* op = out + ((size_t)b * 11 + o) * TT;
#pragma unroll
        for (int t2 = 0; t2 < TT; t2++) {
            float zz = sm[o * 64 + t2];
            scanc(c, v, zz);
            op[t2] = zz;
        }
    }
    __syncthreads();
}

// ================= cooperative mega-kernel ==================================
__global__ __launch_bounds__(256, 4) void snn_mega(
    const float* __restrict__ x,
    const float* __restrict__ c1v, const float* __restrict__ c1g,
    const float* __restrict__ c2v, const float* __restrict__ c2g,
    const float* __restrict__ c3v, const float* __restrict__ c3g,
    const float* __restrict__ d1v, const float* __restrict__ d1g,
    const float* __restrict__ d2v, const float* __restrict__ d2g,
    float* __restrict__ ws, float* __restrict__ out) {
    __shared__ float sm[4 * 16 * 68];
    cg::grid_group grid = cg::this_grid();
    const int bid = blockIdx.x;
    const int G = gridDim.x;

    for (int u = bid; u < 2171 + 4096; u += G)
        st_prep(u, sm, c1v, c1g, c2v, c2g, c3v, c3g, d1v, d1g, d2v, d2g, x, ws);
    grid.sync();
    for (int u = bid; u < 4096; u += G) st_conv1(u, sm, ws);
    grid.sync();
    for (int u = bid; u < 512; u += G) st_conv2(u, sm, ws);
    grid.sync();
    for (int u = bid; u < 512; u += G) st_conv3(u, sm, ws);
    grid.sync();
    for (int u = bid; u < 1028; u += G) st_dense1(u, sm, ws);
    grid.sync();
    for (int u = bid; u < 256; u += G) st_d2part(u, sm, ws);
    grid.sync();
    for (int u = bid; u < 16; u += G) st_d2scan(u, sm, ws, out);
}

// ================= fallback wrappers (R12-equivalent pipeline) ==============
__global__ __launch_bounds__(256) void k_prep(
    const float* __restrict__ x,
    const float* __restrict__ c1v, const float* __restrict__ c1g,
    const float* __restrict__ c2v, const float* __restrict__ c2g,
    const float* __restrict__ c3v, const float* __restrict__ c3g,
    const float* __restrict__ d1v, const float* __restrict__ d1g,
    const float* __restrict__ d2v, const float* __restrict__ d2g,
    float* __restrict__ ws) {
    __shared__ float sm[256];
    st_prep(blockIdx.x, sm, c1v, c1g, c2v, c2g, c3v, c3g, d1v, d1g, d2v, d2g, x, ws);
}
__global__ __launch_bounds__(256) void k_conv1(float* __restrict__ ws) {
    __shared__ float sm[4 * 8 * 68];
    st_conv1(blockIdx.x, sm, ws);
}
__global__ __launch_bounds__(256) void k_conv2(float* __restrict__ ws) {
    __shared__ float sm[4 * 16 * 68];
    st_conv2(blockIdx.x, sm, ws);
}
__global__ __launch_bounds__(256) void k_conv3(float* __restrict__ ws) {
    __shared__ float sm[4 * 8 * 68];
    st_conv3(blockIdx.x, sm, ws);
}
__global__ __launch_bounds__(256) void k_dense1(float* __restrict__ ws) {
    __shared__ float sm[4 * 8 * 68];
    st_dense1(blockIdx.x, sm, ws);
}
__global__ __launch_bounds__(256) void k_d2part(float* __restrict__ ws) {
    __shared__ float sm[4 * 11 * 64];
    st_d2part(blockIdx.x, sm, ws);
}
__global__ __launch_bounds__(256) void k_d2scan(float* __restrict__ ws,
                                                float* __restrict__ out) {
    __shared__ float sm[11 * 64];
    st_d2scan(blockIdx.x, sm, ws, out);
}

extern "C" void kernel_launch(void* const* d_in, const int* in_sizes, int n_in,
                              void* d_out, int out_size, void* d_ws, size_t ws_size,
                              hipStream_t stream) {
    const float* x   = (const float*)d_in[0];
    const float* c1v = (const float*)d_in[1];  const float* c1g = (const float*)d_in[2];
    const float* c2v = (const float*)d_in[3];  const float* c2g = (const float*)d_in[4];
    const float* c3v = (const float*)d_in[5];  const float* c3g = (const float*)d_in[6];
    const float* d1v = (const float*)d_in[7];  const float* d1g = (const float*)d_in[8];
    const float* d2v = (const float*)d_in[9];  const float* d2g = (const float*)d_in[10];
    float* wsf  = (float*)d_ws;
    float* outp = (float*)d_out;
    (void)ws_size; (void)in_sizes; (void)n_in; (void)out_size;

    // Size cooperative grid from the runtime's occupancy answer (grid-stride
    // loops are correct for any grid >= 1); fall back to the proven 7-kernel
    // pipeline if cooperative launch is not possible.
    bool ok = false;
    int dev = 0;
    (void)hipGetDevice(&dev);
    int numCU = 0;
    (void)hipDeviceGetAttribute(&numCU, hipDeviceAttributeMultiprocessorCount, dev);
    int maxB = 0;
    hipError_t oe = hipOccupancyMaxActiveBlocksPerMultiprocessor(
        &maxB, (const void*)snn_mega, 256, 0);
    if (oe == hipSuccess && maxB > 0 && numCU > 0) {
        int grid = maxB * numCU;
        if (grid > 1024) grid = 1024;
        void* args[] = {
            (void*)&x,
            (void*)&c1v, (void*)&c1g, (void*)&c2v, (void*)&c2g,
            (void*)&c3v, (void*)&c3g, (void*)&d1v, (void*)&d1g,
            (void*)&d2v, (void*)&d2g, (void*)&wsf, (void*)&outp,
        };
        hipError_t le = hipLaunchCooperativeKernel((void*)snn_mega, dim3(grid),
                                                   dim3(256), args, 0, stream);
        ok = (le == hipSuccess);
    }
    if (!ok) {
        k_prep  <<<dim3(2171 + 4096), dim3(256), 0, stream>>>(
            x, c1v, c1g, c2v, c2g, c3v, c3g, d1v, d1g, d2v, d2g, wsf);
        k_conv1 <<<dim3(4096), dim3(256), 0, stream>>>(wsf);
        k_conv2 <<<dim3(512),  dim3(256), 0, stream>>>(wsf);
        k_conv3 <<<dim3(512),  dim3(256), 0, stream>>>(wsf);
        k_dense1<<<dim3(1028), dim3(256), 0, stream>>>(wsf);
        k_d2part<<<dim3(256),  dim3(256), 0, stream>>>(wsf);
        k_d2scan<<<dim3(16),   dim3(256), 0, stream>>>(wsf, outp);
    }
}

// Round 17
// 161.866 us; speedup vs baseline: 4.3068x; 4.3068x over previous
//
#include <hip/hip_runtime.h>
#include <cstddef>

#define TT 64  // timesteps

#define RFL(x) __builtin_amdgcn_readfirstlane(x)

typedef unsigned long long u64;

// ---------------- CUBA LIF step helpers ----------------
__device__ __forceinline__ void scanc(float& c, float& v, float& z) {
    c = fmaf(0.7f, c, z);
    v = fmaf(0.75f, v, c);
    float s = (v >= 1.0f) ? 1.0f : 0.0f;
    v = (v >= 1.0f) ? 0.0f : v;
    z = s;
}
__device__ __forceinline__ void scan4(float& c, float& v, float4& a) {
    scanc(c, v, a.x); scanc(c, v, a.y); scanc(c, v, a.z); scanc(c, v, a.w);
}
__device__ __forceinline__ float bit2f(u64 m, int t) {
    return (float)((m >> t) & 1ULL);  // exactly 0.0f or 1.0f
}

// ---------------- prep: weight_norms + x-packing + counter reset ------------
__global__ __launch_bounds__(256) void prep(
    const float* __restrict__ c1v, const float* __restrict__ c1g, float* __restrict__ w1T,
    const float* __restrict__ c2v, const float* __restrict__ c2g, float* __restrict__ w2T,
    const float* __restrict__ c3v, const float* __restrict__ c3g, float* __restrict__ w3T,
    const float* __restrict__ d1v, const float* __restrict__ d1g, float* __restrict__ wd1,
    const float* __restrict__ d2v, const float* __restrict__ d2g, float* __restrict__ wd2P,
    const float* __restrict__ x, u64* __restrict__ xb, unsigned int* __restrict__ cnt) {
    __shared__ float red[256];
    const int bid = blockIdx.x;
    if (bid == 0 && threadIdx.x < 16) cnt[threadIdx.x] = 0u;  // dense2 flags
    if (bid >= 2171) {  // ---- pack path ----
        const int sub = threadIdx.x & 15;
        const int grp = threadIdx.x >> 4;  // 16 pixel-slots
        const int pb = bid - 2171;         // 0..4095
#pragma unroll
        for (int it = 0; it < 4; it++) {
            const size_t base = ((size_t)pb * 4 + it) * 32;  // 32 pixels/iter
            const size_t p0 = base + grp;
            const size_t p1 = base + 16 + grp;
            const float4 v0 = *(const float4*)(x + p0 * TT + sub * 4);
            const float4 v1 = *(const float4*)(x + p1 * TT + sub * 4);
            const unsigned int n0 = (v0.x > 0.5f ? 1u : 0u) | (v0.y > 0.5f ? 2u : 0u) |
                                    (v0.z > 0.5f ? 4u : 0u) | (v0.w > 0.5f ? 8u : 0u);
            const unsigned int n1 = (v1.x > 0.5f ? 1u : 0u) | (v1.y > 0.5f ? 2u : 0u) |
                                    (v1.z > 0.5f ? 4u : 0u) | (v1.w > 0.5f ? 8u : 0u);
            u64 w0 = (u64)n0 << (4 * sub);
            u64 w1 = (u64)n1 << (4 * sub);
            w0 |= __shfl_xor(w0, 1); w1 |= __shfl_xor(w1, 1);
            w0 |= __shfl_xor(w0, 2); w1 |= __shfl_xor(w1, 2);
            w0 |= __shfl_xor(w0, 4); w1 |= __shfl_xor(w1, 4);
            w0 |= __shfl_xor(w0, 8); w1 |= __shfl_xor(w1, 8);
            if (sub == 0) { xb[p0] = w0; xb[p1] = w1; }
        }
        return;
    }
    // ---- weight_norm path ----
    const float *v, *g; float* w; int o, K, LD; bool tr;
    if (bid < 8)         { v = c1v; g = c1g; w = w1T;  o = bid;        K = 50;   LD = 8;  tr = true;  }
    else if (bid < 40)   { v = c2v; g = c2g; w = w2T;  o = bid - 8;    K = 200;  LD = 32; tr = true;  }
    else if (bid < 104)  { v = c3v; g = c3g; w = w3T;  o = bid - 40;   K = 800;  LD = 64; tr = true;  }
    else if (bid < 2160) { v = d1v; g = d1g; w = wd1;  o = bid - 104;  K = 256;  LD = 0;  tr = false; }
    else                 { v = d2v; g = d2g; w = wd2P; o = bid - 2160; K = 2056; LD = 12; tr = true;  }

    float s = 0.f;
    for (int k = threadIdx.x; k < K; k += 256) {
        float xx = v[(size_t)o * K + k];
        s += xx * xx;
    }
    red[threadIdx.x] = s;
    __syncthreads();
    for (int off = 128; off > 0; off >>= 1) {
        if (threadIdx.x < off) red[threadIdx.x] += red[threadIdx.x + off];
        __syncthreads();
    }
    const float scale = g[o] / sqrtf(red[0]);
    for (int k = threadIdx.x; k < K; k += 256) {
        float val = scale * v[(size_t)o * K + k];
        if (tr) w[(size_t)k * LD + o] = val;
        else    w[(size_t)o * K + k] = val;
    }
}

// ---------------- conv1 (2->8) bits in, bits out, fused CUBA ----------------
__global__ __launch_bounds__(256) void conv1_cuba(const u64* __restrict__ xb,
                                                  const float* __restrict__ w1T,
                                                  u64* __restrict__ s1b) {
    __shared__ float lds[4][8][68];
    const int wid = RFL(threadIdx.x >> 6), t = threadIdx.x & 63;
    const int task = RFL(blockIdx.x) * 4 + wid;  // 0..16383
    const int spi = task & 1023, b = task >> 10;
    const int oy = spi >> 5, ox = spi & 31;

    float a0=0,a1=0,a2=0,a3=0,a4=0,a5=0,a6=0,a7=0;
    const u64* xq = xb + (size_t)b * 2 * 16384;

    if (oy >= 1 && ox >= 1) {
        const u64* xi = xq + (size_t)(oy * 4 - 1) * 128 + (ox * 4 - 1);
        for (int ci = 0; ci < 2; ci++) {
            u64 m[25];
#pragma unroll
            for (int ky = 0; ky < 5; ky++)
#pragma unroll
                for (int kx = 0; kx < 5; kx++)
                    m[ky * 5 + kx] = xi[ci * 16384 + ky * 128 + kx];
#pragma unroll
            for (int k = 0; k < 25; k++) {
                const float xvk = bit2f(m[k], t);
                const float4* wp = (const float4*)(w1T + (ci * 25 + k) * 8);
                const float4 wA = wp[0], wB = wp[1];
                a0 = fmaf(wA.x, xvk, a0); a1 = fmaf(wA.y, xvk, a1);
                a2 = fmaf(wA.z, xvk, a2); a3 = fmaf(wA.w, xvk, a3);
                a4 = fmaf(wB.x, xvk, a4); a5 = fmaf(wB.y, xvk, a5);
                a6 = fmaf(wB.z, xvk, a6); a7 = fmaf(wB.w, xvk, a7);
            }
        }
    } else {
        for (int ci = 0; ci < 2; ci++) {
#pragma unroll
            for (int ky = 0; ky < 5; ky++) {
                const int iy = oy * 4 + ky - 1;
                if (iy < 0 || iy >= 128) continue;
#pragma unroll
                for (int kx = 0; kx < 5; kx++) {
                    const int ix = ox * 4 + kx - 1;
                    if (ix < 0 || ix >= 128) continue;
                    const float xvk = bit2f(xq[ci * 16384 + iy * 128 + ix], t);
                    const float4* wp = (const float4*)(w1T + (ci * 25 + ky * 5 + kx) * 8);
                    const float4 wA = wp[0], wB = wp[1];
                    a0 = fmaf(wA.x, xvk, a0); a1 = fmaf(wA.y, xvk, a1);
                    a2 = fmaf(wA.z, xvk, a2); a3 = fmaf(wA.w, xvk, a3);
                    a4 = fmaf(wB.x, xvk, a4); a5 = fmaf(wB.y, xvk, a5);
                    a6 = fmaf(wB.z, xvk, a6); a7 = fmaf(wB.w, xvk, a7);
                }
            }
        }
    }
    lds[wid][0][t] = a0; lds[wid][1][t] = a1; lds[wid][2][t] = a2; lds[wid][3][t] = a3;
    lds[wid][4][t] = a4; lds[wid][5][t] = a5; lds[wid][6][t] = a6; lds[wid][7][t] = a7;
    __syncthreads();
    if (t < 8) {  // scan channel t in-register, write spikes back to LDS
        float* row = &lds[wid][t][0];
        float c = 0.f, v = 0.f;
        for (int tc = 0; tc < 4; tc++) {
            float4 r0 = *(const float4*)&row[tc * 16 + 0];
            float4 r1 = *(const float4*)&row[tc * 16 + 4];
            float4 r2 = *(const float4*)&row[tc * 16 + 8];
            float4 r3 = *(const float4*)&row[tc * 16 + 12];
            scan4(c, v, r0); scan4(c, v, r1); scan4(c, v, r2); scan4(c, v, r3);
            *(float4*)&row[tc * 16 + 0] = r0; *(float4*)&row[tc * 16 + 4] = r1;
            *(float4*)&row[tc * 16 + 8] = r2; *(float4*)&row[tc * 16 + 12] = r3;
        }
    }
    __syncthreads();
    u64* ob = s1b + (size_t)b * 8 * 1024 + spi;
#pragma unroll
    for (int ch = 0; ch < 8; ch++) {
        const u64 m = __ballot(lds[wid][ch][t] > 0.5f);
        if (t == 0) ob[(size_t)ch * 1024] = m;
    }
}

// ---------------- conv2 (8->32) bits in, FLOAT out, fused CUBA --------------
__global__ __launch_bounds__(256) void conv2_cuba(const u64* __restrict__ s1b,
                                                  const float* __restrict__ w2T,
                                                  float* __restrict__ s2) {
    __shared__ float lds[4][16][68];
    const int wid = RFL(threadIdx.x >> 6), t = threadIdx.x & 63;
    const int task = RFL(blockIdx.x) * 4 + wid;  // 0..2047
    const int og = task & 1;
    const int spi = (task >> 1) & 63;
    const int b = task >> 7;
    const int oy = spi >> 3, ox = spi & 7;

    float a[16];
#pragma unroll
    for (int j = 0; j < 16; j++) a[j] = 0.f;
    const u64* sb = s1b + (size_t)b * 8 * 1024;

    if (oy >= 1 && ox >= 1) {
        const u64* si = sb + (size_t)(oy * 4 - 1) * 32 + (ox * 4 - 1);
        for (int ci = 0; ci < 8; ci++) {
            u64 m[25];
#pragma unroll
            for (int ky = 0; ky < 5; ky++)
#pragma unroll
                for (int kx = 0; kx < 5; kx++)
                    m[ky * 5 + kx] = si[ci * 1024 + ky * 32 + kx];
#pragma unroll
            for (int k = 0; k < 25; k++) {
                const float xvk = bit2f(m[k], t);
                const float4* wp = (const float4*)(w2T + (ci * 25 + k) * 32 + og * 16);
                const float4 w0 = wp[0], w1 = wp[1], w2 = wp[2], w3 = wp[3];
                a[0]  = fmaf(w0.x, xvk, a[0]);  a[1]  = fmaf(w0.y, xvk, a[1]);
                a[2]  = fmaf(w0.z, xvk, a[2]);  a[3]  = fmaf(w0.w, xvk, a[3]);
                a[4]  = fmaf(w1.x, xvk, a[4]);  a[5]  = fmaf(w1.y, xvk, a[5]);
                a[6]  = fmaf(w1.z, xvk, a[6]);  a[7]  = fmaf(w1.w, xvk, a[7]);
                a[8]  = fmaf(w2.x, xvk, a[8]);  a[9]  = fmaf(w2.y, xvk, a[9]);
                a[10] = fmaf(w2.z, xvk, a[10]); a[11] = fmaf(w2.w, xvk, a[11]);
                a[12] = fmaf(w3.x, xvk, a[12]); a[13] = fmaf(w3.y, xvk, a[13]);
                a[14] = fmaf(w3.z, xvk, a[14]); a[15] = fmaf(w3.w, xvk, a[15]);
            }
        }
    } else {
        for (int ci = 0; ci < 8; ci++) {
#pragma unroll
            for (int ky = 0; ky < 5; ky++) {
                const int iy = oy * 4 + ky - 1;
                if (iy < 0 || iy >= 32) continue;
#pragma unroll
                for (int kx = 0; kx < 5; kx++) {
                    const int ix = ox * 4 + kx - 1;
                    if (ix < 0 || ix >= 32) continue;
                    const float xvk = bit2f(sb[ci * 1024 + iy * 32 + ix], t);
                    const float4* wp =
                        (const float4*)(w2T + (ci * 25 + ky * 5 + kx) * 32 + og * 16);
                    const float4 w0 = wp[0], w1 = wp[1], w2 = wp[2], w3 = wp[3];
                    a[0]  = fmaf(w0.x, xvk, a[0]);  a[1]  = fmaf(w0.y, xvk, a[1]);
                    a[2]  = fmaf(w0.z, xvk, a[2]);  a[3]  = fmaf(w0.w, xvk, a[3]);
                    a[4]  = fmaf(w1.x, xvk, a[4]);  a[5]  = fmaf(w1.y, xvk, a[5]);
                    a[6]  = fmaf(w1.z, xvk, a[6]);  a[7]  = fmaf(w1.w, xvk, a[7]);
                    a[8]  = fmaf(w2.x, xvk, a[8]);  a[9]  = fmaf(w2.y, xvk, a[9]);
                    a[10] = fmaf(w2.z, xvk, a[10]); a[11] = fmaf(w2.w, xvk, a[11]);
                    a[12] = fmaf(w3.x, xvk, a[12]); a[13] = fmaf(w3.y, xvk, a[13]);
                    a[14] = fmaf(w3.z, xvk, a[14]); a[15] = fmaf(w3.w, xvk, a[15]);
                }
            }
        }
    }
#pragma unroll
    for (int j = 0; j < 16; j++) lds[wid][j][t] = a[j];
    __syncthreads();
    if (t < 16) {
        float* row = &lds[wid][t][0];
        float c = 0.f, v = 0.f;
        float4* op = (float4*)(s2 + (((size_t)b * 32 + og * 16 + t) * 64 + spi) * TT);
        for (int tc = 0; tc < 4; tc++) {
            float4 r0 = *(const float4*)&row[tc * 16 + 0];
            float4 r1 = *(const float4*)&row[tc * 16 + 4];
            float4 r2 = *(const float4*)&row[tc * 16 + 8];
            float4 r3 = *(const float4*)&row[tc * 16 + 12];
            scan4(c, v, r0); scan4(c, v, r1); scan4(c, v, r2); scan4(c, v, r3);
            op[tc * 4 + 0] = r0; op[tc * 4 + 1] = r1;
            op[tc * 4 + 2] = r2; op[tc * 4 + 3] = r3;
        }
    }
}

// ---------------- conv3 (32->64) float in/out, fused CUBA -------------------
template <int OY, int OX>
__device__ __forceinline__ void conv3_acc(const float* __restrict__ xb,
                                          const float* __restrict__ wTo,
                                          int wid, float* __restrict__ acc) {
    constexpr int KY0 = (OY == 0) ? 1 : 0;
    constexpr int KX0 = (OX == 0) ? 1 : 0;
    constexpr int NKY = 5 - KY0;
    constexpr int NKX = 5 - KX0;
    for (int c8 = 0; c8 < 8; c8++) {
        const int ci = wid * 8 + c8;
        float xv[NKY * NKX];
#pragma unroll
        for (int ky = KY0; ky < 5; ky++) {
#pragma unroll
            for (int kx = KX0; kx < 5; kx++) {
                const int iy = OY * 4 + ky - 1;
                const int ix = OX * 4 + kx - 1;
                xv[(ky - KY0) * NKX + (kx - KX0)] =
                    xb[((size_t)((ci * 8 + iy) * 8 + ix)) * TT];
            }
        }
#pragma unroll
        for (int ky = KY0; ky < 5; ky++) {
#pragma unroll
            for (int kx = KX0; kx < 5; kx++) {
                const float xvk = xv[(ky - KY0) * NKX + (kx - KX0)];
                const float4* wp = (const float4*)(wTo + (ci * 25 + ky * 5 + kx) * 64);
                const float4 wA = wp[0], wB = wp[1];
                acc[0] = fmaf(wA.x, xvk, acc[0]); acc[1] = fmaf(wA.y, xvk, acc[1]);
                acc[2] = fmaf(wA.z, xvk, acc[2]); acc[3] = fmaf(wA.w, xvk, acc[3]);
                acc[4] = fmaf(wB.x, xvk, acc[4]); acc[5] = fmaf(wB.y, xvk, acc[5]);
                acc[6] = fmaf(wB.z, xvk, acc[6]); acc[7] = fmaf(wB.w, xvk, acc[7]);
            }
        }
    }
}

__global__ __launch_bounds__(256) void conv3_cuba(const float* __restrict__ s2,
                                                  const float* __restrict__ wT,
                                                  float* __restrict__ s3) {
    __shared__ float red[4][8][68];
    const int wid = RFL(threadIdx.x >> 6), t = threadIdx.x & 63;
    const int og = RFL(blockIdx.x) & 7;
    const int spi = (RFL(blockIdx.x) >> 3) & 3;
    const int b = RFL(blockIdx.x) >> 5;

    float acc[8];
#pragma unroll
    for (int j = 0; j < 8; j++) acc[j] = 0.f;
    const float* xb = s2 + (size_t)b * 32 * 8 * 8 * TT + t;
    const float* wTo = wT + og * 8;

    switch (spi) {
        case 0: conv3_acc<0, 0>(xb, wTo, wid, acc); break;
        case 1: conv3_acc<0, 1>(xb, wTo, wid, acc); break;
        case 2: conv3_acc<1, 0>(xb, wTo, wid, acc); break;
        default: conv3_acc<1, 1>(xb, wTo, wid, acc); break;
    }
#pragma unroll
    for (int j = 0; j < 8; j++) red[wid][j][t] = acc[j];
    __syncthreads();
    if (wid == 0) {
#pragma unroll
        for (int j = 0; j < 8; j++)
            red[0][j][t] = ((red[0][j][t] + red[1][j][t]) + red[2][j][t]) + red[3][j][t];
    }
    __syncthreads();
    if (threadIdx.x < 8) {
        const int j = threadIdx.x;
        float* row = &red[0][j][0];
        float c = 0.f, v = 0.f;
        float4* op = (float4*)(s3 + ((size_t)b * 256 + og * 32 + j * 4 + spi) * TT);
        for (int tc = 0; tc < 4; tc++) {
            float4 r0 = *(const float4*)&row[tc * 16 + 0];
            float4 r1 = *(const float4*)&row[tc * 16 + 4];
            float4 r2 = *(const float4*)&row[tc * 16 + 8];
            float4 r3 = *(const float4*)&row[tc * 16 + 12];
            scan4(c, v, r0); scan4(c, v, r1); scan4(c, v, r2); scan4(c, v, r3);
            op[tc * 4 + 0] = r0; op[tc * 4 + 1] = r1;
            op[tc * 4 + 2] = r2; op[tc * 4 + 3] = r3;
        }
    }
}

// ---------------- dense1 (256 -> 2056) float in/out, fused CUBA -------------
__global__ __launch_bounds__(256) void dense1_cuba(const float* __restrict__ s3,
                                                   const float* __restrict__ w,
                                                   float* __restrict__ s4) {
    __shared__ float lds[4][8][68];
    const int wid = threadIdx.x >> 6, t = threadIdx.x & 63;
    const int task = blockIdx.x * 4 + wid;  // 0..4111  (16 b x 257 og)
    const int bq = task / 257;
    const int ogq = task - bq * 257;
    const int b = RFL(bq);
    const int o0 = RFL(ogq * 8);

    float a0=0,a1=0,a2=0,a3=0,a4=0,a5=0,a6=0,a7=0;
    const float* ab = s3 + (size_t)b * 256 * TT + t;
    const float* r0 = w + (size_t)(o0 + 0) * 256;
    const float* r1 = w + (size_t)(o0 + 1) * 256;
    const float* r2 = w + (size_t)(o0 + 2) * 256;
    const float* r3 = w + (size_t)(o0 + 3) * 256;
    const float* r4 = w + (size_t)(o0 + 4) * 256;
    const float* r5 = w + (size_t)(o0 + 5) * 256;
    const float* r6 = w + (size_t)(o0 + 6) * 256;
    const float* r7 = w + (size_t)(o0 + 7) * 256;

#pragma unroll 2
    for (int i = 0; i < 256; i += 4) {
        const float av0 = ab[(size_t)(i + 0) * TT];
        const float av1 = ab[(size_t)(i + 1) * TT];
        const float av2 = ab[(size_t)(i + 2) * TT];
        const float av3 = ab[(size_t)(i + 3) * TT];
        const float4 q0 = *(const float4*)(r0 + i);
        const float4 q1 = *(const float4*)(r1 + i);
        const float4 q2 = *(const float4*)(r2 + i);
        const float4 q3 = *(const float4*)(r3 + i);
        const float4 q4 = *(const float4*)(r4 + i);
        const float4 q5 = *(const float4*)(r5 + i);
        const float4 q6 = *(const float4*)(r6 + i);
        const float4 q7 = *(const float4*)(r7 + i);
        a0 = fmaf(q0.x, av0, a0); a1 = fmaf(q1.x, av0, a1);
        a2 = fmaf(q2.x, av0, a2); a3 = fmaf(q3.x, av0, a3);
        a4 = fmaf(q4.x, av0, a4); a5 = fmaf(q5.x, av0, a5);
        a6 = fmaf(q6.x, av0, a6); a7 = fmaf(q7.x, av0, a7);
        a0 = fmaf(q0.y, av1, a0); a1 = fmaf(q1.y, av1, a1);
        a2 = fmaf(q2.y, av1, a2); a3 = fmaf(q3.y, av1, a3);
        a4 = fmaf(q4.y, av1, a4); a5 = fmaf(q5.y, av1, a5);
        a6 = fmaf(q6.y, av1, a6); a7 = fmaf(q7.y, av1, a7);
        a0 = fmaf(q0.z, av2, a0); a1 = fmaf(q1.z, av2, a1);
        a2 = fmaf(q2.z, av2, a2); a3 = fmaf(q3.z, av2, a3);
        a4 = fmaf(q4.z, av2, a4); a5 = fmaf(q5.z, av2, a5);
        a6 = fmaf(q6.z, av2, a6); a7 = fmaf(q7.z, av2, a7);
        a0 = fmaf(q0.w, av3, a0); a1 = fmaf(q1.w, av3, a1);
        a2 = fmaf(q2.w, av3, a2); a3 = fmaf(q3.w, av3, a3);
        a4 = fmaf(q4.w, av3, a4); a5 = fmaf(q5.w, av3, a5);
        a6 = fmaf(q6.w, av3, a6); a7 = fmaf(q7.w, av3, a7);
    }
    lds[wid][0][t] = a0; lds[wid][1][t] = a1; lds[wid][2][t] = a2; lds[wid][3][t] = a3;
    lds[wid][4][t] = a4; lds[wid][5][t] = a5; lds[wid][6][t] = a6; lds[wid][7][t] = a7;
    __syncthreads();
    if (t < 8) {
        float* row = &lds[wid][t][0];
        float c = 0.f, v = 0.f;
        float4* op = (float4*)(s4 + ((size_t)b * 2056 + o0 + t) * TT);
        for (int tc = 0; tc < 4; tc++) {
            float4 r0q = *(const float4*)&row[tc * 16 + 0];
            float4 r1q = *(const float4*)&row[tc * 16 + 4];
            float4 r2q = *(const float4*)&row[tc * 16 + 8];
            float4 r3q = *(const float4*)&row[tc * 16 + 12];
            scan4(c, v, r0q); scan4(c, v, r1q); scan4(c, v, r2q); scan4(c, v, r3q);
            op[tc * 4 + 0] = r0q; op[tc * 4 + 1] = r1q;
            op[tc * 4 + 2] = r2q; op[tc * 4 + 3] = r3q;
        }
    }
}

// ---------------- dense2 fused: split-K partials + last-block scan ----------
// grid (16 sp, 16 b). Each block computes its split's partials (identical to
// R12 dense2_part), publishes them (fence + device atomic), and the 16th
// arriver for batch b performs the fixed-sp-order reduce + final CUBA scan
// (identical math to R12 dense2_scan, order-independent of arrival).
__global__ __launch_bounds__(256) void dense2_fused(const float* __restrict__ s4,
                                                    const float* __restrict__ wP,
                                                    float* __restrict__ z4p,
                                                    unsigned int* __restrict__ cnt,
                                                    float* __restrict__ out) {
    __shared__ float red[4][11][64];
    __shared__ unsigned int rank;
    const int sp = blockIdx.x, b = blockIdx.y;
    const int w = threadIdx.x >> 6, t = threadIdx.x & 63;
    const int i0 = sp * 129;
    const int iend = (i0 + 129 < 2056) ? i0 + 129 : 2056;
    const float* src = s4 + (size_t)b * 2056 * TT + t;

    float acc[11];
#pragma unroll
    for (int j = 0; j < 11; j++) acc[j] = 0.f;

#pragma unroll 4
    for (int i = i0 + w; i < iend; i += 4) {
        const float xv = src[(size_t)i * TT];
        const float4* wp = (const float4*)(wP + (size_t)i * 12);
        const float4 w0 = wp[0], w1 = wp[1], w2 = wp[2];
        acc[0]  = fmaf(w0.x, xv, acc[0]);  acc[1]  = fmaf(w0.y, xv, acc[1]);
        acc[2]  = fmaf(w0.z, xv, acc[2]);  acc[3]  = fmaf(w0.w, xv, acc[3]);
        acc[4]  = fmaf(w1.x, xv, acc[4]);  acc[5]  = fmaf(w1.y, xv, acc[5]);
        acc[6]  = fmaf(w1.z, xv, acc[6]);  acc[7]  = fmaf(w1.w, xv, acc[7]);
        acc[8]  = fmaf(w2.x, xv, acc[8]);  acc[9]  = fmaf(w2.y, xv, acc[9]);
        acc[10] = fmaf(w2.z, xv, acc[10]);
    }
#pragma unroll
    for (int j = 0; j < 11; j++) red[w][j][t] = acc[j];
    __syncthreads();
    if (w == 0) {
#pragma unroll
        for (int j = 0; j < 11; j++) {
            const float s = red[0][j][t] + red[1][j][t] + red[2][j][t] + red[3][j][t];
            z4p[(((size_t)b * 16 + sp) * 11 + j) * TT + t] = s;
        }
    }
    __syncthreads();  // drains vmcnt: all partial stores issued & retired
    if (threadIdx.x == 0) {
        __threadfence();  // release: flush this XCD's L2 to device scope
        rank = atomicAdd(&cnt[b], 1u);
    }
    __syncthreads();
    if (rank == 15u) {  // last block for this batch does the reduce + scan
        __threadfence();  // acquire: invalidate stale cached lines
        float* zs = &red[0][0][0];  // reuse LDS: 11*64 sums
        for (int idx = threadIdx.x; idx < 11 * 64; idx += 256) {
            const int o = idx >> 6, tt = idx & 63;
            float s = 0.f;
#pragma unroll
            for (int p = 0; p < 16; p++)
                s += z4p[(((size_t)b * 16 + p) * 11 + o) * TT + tt];
            zs[o * 64 + tt] = s;
        }
        __syncthreads();
        if (threadIdx.x < 11) {
            const int o = threadIdx.x;
            float c = 0.f, v = 0.f;
            float* op = out + ((size_t)b * 11 + o) * TT;
#pragma unroll
            for (int t2 = 0; t2 < TT; t2++) {
                float zz = zs[o * 64 + t2];
                scanc(c, v, zz);
                op[t2] = zz;
            }
        }
    }
}

extern "C" void kernel_launch(void* const* d_in, const int* in_sizes, int n_in,
                              void* d_out, int out_size, void* d_ws, size_t ws_size,
                              hipStream_t stream) {
    const float* x   = (const float*)d_in[0];
    const float* c1v = (const float*)d_in[1];  const float* c1g = (const float*)d_in[2];
    const float* c2v = (const float*)d_in[3];  const float* c2g = (const float*)d_in[4];
    const float* c3v = (const float*)d_in[5];  const float* c3g = (const float*)d_in[6];
    const float* d1v = (const float*)d_in[7];  const float* d1g = (const float*)d_in[8];
    const float* d2v = (const float*)d_in[9];  const float* d2g = (const float*)d_in[10];

    float* ws = (float*)d_ws;
    // weight region
    float* w1T  = ws + 0;        // (50,8)     = 400
    float* w2T  = ws + 400;      // (200,32)   = 6400
    float* w3T  = ws + 6800;     // (800,64)   = 51200
    float* wd1  = ws + 58000;    // (2056,256) original layout = 526336
    float* wd2P = ws + 584336;   // (2056,12) padded = 24672
    // float activation regions (R12 layout)
    float* A = ws + 609008;
    float* B = A + 8388608;
    float* s3  = A;              // dense-in spikes (b,256,t)
    float* s4  = A + 262144;     // dense1 spikes (b,2056,t)
    float* s2  = B;              // conv2 spikes (b,32,8,8,t)
    float* z4p = B + 2097152;    // dense2 partials (b,16,11,t) = 180224
    // bitmask regions (even float offsets -> 8B aligned)
    u64* xbits  = (u64*)(ws + 13191920);  // 524288 u64
    u64* s1bits = (u64*)(ws + 14240496);  // 131072 u64 -> ends 14502640
    unsigned int* cnt = (unsigned int*)(ws + 14502640);  // 16 flags
    (void)ws_size; (void)in_sizes; (void)n_in; (void)out_size;

    prep<<<dim3(2171 + 4096), dim3(256), 0, stream>>>(
        c1v, c1g, w1T, c2v, c2g, w2T, c3v, c3g, w3T, d1v, d1g, wd1,
        d2v, d2g, wd2P, x, xbits, cnt);

    conv1_cuba  <<<dim3(4096),   dim3(256), 0, stream>>>(xbits, w1T, s1bits);
    conv2_cuba  <<<dim3(512),    dim3(256), 0, stream>>>(s1bits, w2T, s2);
    conv3_cuba  <<<dim3(512),    dim3(256), 0, stream>>>(s2, w3T, s3);
    dense1_cuba <<<dim3(1028),   dim3(256), 0, stream>>>(s3, wd1, s4);
    dense2_fused<<<dim3(16, 16), dim3(256), 0, stream>>>(s4, wd2P, z4p, cnt,
                                                         (float*)d_out);
}

// Round 18
// 152.747 us; speedup vs baseline: 4.5639x; 1.0597x over previous
//
#include <hip/hip_runtime.h>
#include <cstddef>

#define TT 64  // timesteps

#define RFL(x) __builtin_amdgcn_readfirstlane(x)

typedef unsigned long long u64;

// ---------------- CUBA LIF step helpers ----------------
__device__ __forceinline__ void scanc(float& c, float& v, float& z) {
    c = fmaf(0.7f, c, z);
    v = fmaf(0.75f, v, c);
    float s = (v >= 1.0f) ? 1.0f : 0.0f;
    v = (v >= 1.0f) ? 0.0f : v;
    z = s;
}
__device__ __forceinline__ void scan4(float& c, float& v, float4& a) {
    scanc(c, v, a.x); scanc(c, v, a.y); scanc(c, v, a.z); scanc(c, v, a.w);
}
__device__ __forceinline__ float bit2f(u64 m, int t) {
    return (float)((m >> t) & 1ULL);  // exactly 0.0f or 1.0f
}

// ---------------- prep: all weight_norms + x-packing in ONE dispatch --------
// Blocks 0..2170: weight_norm segments (identical math to previous rounds).
// Blocks 2171..6266: pack x into per-pixel time bitmasks — 16-lane group per
// pixel, 2 pixels per thread per iteration (loads issued before the shfl
// chains -> 2x memory-level parallelism). Bit t == (x[t] > 0.5), same layout.
__global__ __launch_bounds__(256) void prep(
    const float* __restrict__ c1v, const float* __restrict__ c1g, float* __restrict__ w1T,
    const float* __restrict__ c2v, const float* __restrict__ c2g, float* __restrict__ w2T,
    const float* __restrict__ c3v, const float* __restrict__ c3g, float* __restrict__ w3T,
    const float* __restrict__ d1v, const float* __restrict__ d1g, float* __restrict__ wd1,
    const float* __restrict__ d2v, const float* __restrict__ d2g, float* __restrict__ wd2P,
    const float* __restrict__ x, u64* __restrict__ xb) {
    __shared__ float red[256];
    const int bid = blockIdx.x;
    if (bid >= 2171) {  // ---- pack path ----
        const int sub = threadIdx.x & 15;
        const int grp = threadIdx.x >> 4;  // 16 pixel-slots
        const int pb = bid - 2171;         // 0..4095
#pragma unroll
        for (int it = 0; it < 4; it++) {
            const size_t base = ((size_t)pb * 4 + it) * 32;  // 32 pixels/iter
            const size_t p0 = base + grp;
            const size_t p1 = base + 16 + grp;
            const float4 v0 = *(const float4*)(x + p0 * TT + sub * 4);
            const float4 v1 = *(const float4*)(x + p1 * TT + sub * 4);
            const unsigned int n0 = (v0.x > 0.5f ? 1u : 0u) | (v0.y > 0.5f ? 2u : 0u) |
                                    (v0.z > 0.5f ? 4u : 0u) | (v0.w > 0.5f ? 8u : 0u);
            const unsigned int n1 = (v1.x > 0.5f ? 1u : 0u) | (v1.y > 0.5f ? 2u : 0u) |
                                    (v1.z > 0.5f ? 4u : 0u) | (v1.w > 0.5f ? 8u : 0u);
            u64 w0 = (u64)n0 << (4 * sub);
            u64 w1 = (u64)n1 << (4 * sub);
            w0 |= __shfl_xor(w0, 1); w1 |= __shfl_xor(w1, 1);
            w0 |= __shfl_xor(w0, 2); w1 |= __shfl_xor(w1, 2);
            w0 |= __shfl_xor(w0, 4); w1 |= __shfl_xor(w1, 4);
            w0 |= __shfl_xor(w0, 8); w1 |= __shfl_xor(w1, 8);
            if (sub == 0) { xb[p0] = w0; xb[p1] = w1; }
        }
        return;
    }
    // ---- weight_norm path ----
    const float *v, *g; float* w; int o, K, LD; bool tr;
    if (bid < 8)         { v = c1v; g = c1g; w = w1T;  o = bid;        K = 50;   LD = 8;  tr = true;  }
    else if (bid < 40)   { v = c2v; g = c2g; w = w2T;  o = bid - 8;    K = 200;  LD = 32; tr = true;  }
    else if (bid < 104)  { v = c3v; g = c3g; w = w3T;  o = bid - 40;   K = 800;  LD = 64; tr = true;  }
    else if (bid < 2160) { v = d1v; g = d1g; w = wd1;  o = bid - 104;  K = 256;  LD = 0;  tr = false; }
    else                 { v = d2v; g = d2g; w = wd2P; o = bid - 2160; K = 2056; LD = 12; tr = true;  }

    float s = 0.f;
    for (int k = threadIdx.x; k < K; k += 256) {
        float xx = v[(size_t)o * K + k];
        s += xx * xx;
    }
    red[threadIdx.x] = s;
    __syncthreads();
    for (int off = 128; off > 0; off >>= 1) {
        if (threadIdx.x < off) red[threadIdx.x] += red[threadIdx.x + off];
        __syncthreads();
    }
    const float scale = g[o] / sqrtf(red[0]);
    for (int k = threadIdx.x; k < K; k += 256) {
        float val = scale * v[(size_t)o * K + k];
        if (tr) w[(size_t)k * LD + o] = val;
        else    w[(size_t)o * K + k] = val;
    }
}

// ---------------- conv1 (2->8) bits in, bits out, fused CUBA ----------------
__global__ __launch_bounds__(256) void conv1_cuba(const u64* __restrict__ xb,
                                                  const float* __restrict__ w1T,
                                                  u64* __restrict__ s1b) {
    __shared__ float lds[4][8][68];
    const int wid = RFL(threadIdx.x >> 6), t = threadIdx.x & 63;
    const int task = RFL(blockIdx.x) * 4 + wid;  // 0..16383
    const int spi = task & 1023, b = task >> 10;
    const int oy = spi >> 5, ox = spi & 31;

    float a0=0,a1=0,a2=0,a3=0,a4=0,a5=0,a6=0,a7=0;
    const u64* xq = xb + (size_t)b * 2 * 16384;

    if (oy >= 1 && ox >= 1) {
        const u64* xi = xq + (size_t)(oy * 4 - 1) * 128 + (ox * 4 - 1);
        for (int ci = 0; ci < 2; ci++) {
            u64 m[25];
#pragma unroll
            for (int ky = 0; ky < 5; ky++)
#pragma unroll
                for (int kx = 0; kx < 5; kx++)
                    m[ky * 5 + kx] = xi[ci * 16384 + ky * 128 + kx];
#pragma unroll
            for (int k = 0; k < 25; k++) {
                const float xvk = bit2f(m[k], t);
                const float4* wp = (const float4*)(w1T + (ci * 25 + k) * 8);
                const float4 wA = wp[0], wB = wp[1];
                a0 = fmaf(wA.x, xvk, a0); a1 = fmaf(wA.y, xvk, a1);
                a2 = fmaf(wA.z, xvk, a2); a3 = fmaf(wA.w, xvk, a3);
                a4 = fmaf(wB.x, xvk, a4); a5 = fmaf(wB.y, xvk, a5);
                a6 = fmaf(wB.z, xvk, a6); a7 = fmaf(wB.w, xvk, a7);
            }
        }
    } else {
        for (int ci = 0; ci < 2; ci++) {
#pragma unroll
            for (int ky = 0; ky < 5; ky++) {
                const int iy = oy * 4 + ky - 1;
                if (iy < 0 || iy >= 128) continue;
#pragma unroll
                for (int kx = 0; kx < 5; kx++) {
                    const int ix = ox * 4 + kx - 1;
                    if (ix < 0 || ix >= 128) continue;
                    const float xvk = bit2f(xq[ci * 16384 + iy * 128 + ix], t);
                    const float4* wp = (const float4*)(w1T + (ci * 25 + ky * 5 + kx) * 8);
                    const float4 wA = wp[0], wB = wp[1];
                    a0 = fmaf(wA.x, xvk, a0); a1 = fmaf(wA.y, xvk, a1);
                    a2 = fmaf(wA.z, xvk, a2); a3 = fmaf(wA.w, xvk, a3);
                    a4 = fmaf(wB.x, xvk, a4); a5 = fmaf(wB.y, xvk, a5);
                    a6 = fmaf(wB.z, xvk, a6); a7 = fmaf(wB.w, xvk, a7);
                }
            }
        }
    }
    lds[wid][0][t] = a0; lds[wid][1][t] = a1; lds[wid][2][t] = a2; lds[wid][3][t] = a3;
    lds[wid][4][t] = a4; lds[wid][5][t] = a5; lds[wid][6][t] = a6; lds[wid][7][t] = a7;
    __syncthreads();
    if (t < 8) {  // scan channel t in-register, write spikes back to LDS
        float* row = &lds[wid][t][0];
        float c = 0.f, v = 0.f;
        for (int tc = 0; tc < 4; tc++) {
            float4 r0 = *(const float4*)&row[tc * 16 + 0];
            float4 r1 = *(const float4*)&row[tc * 16 + 4];
            float4 r2 = *(const float4*)&row[tc * 16 + 8];
            float4 r3 = *(const float4*)&row[tc * 16 + 12];
            scan4(c, v, r0); scan4(c, v, r1); scan4(c, v, r2); scan4(c, v, r3);
            *(float4*)&row[tc * 16 + 0] = r0; *(float4*)&row[tc * 16 + 4] = r1;
            *(float4*)&row[tc * 16 + 8] = r2; *(float4*)&row[tc * 16 + 12] = r3;
        }
    }
    __syncthreads();
    u64* ob = s1b + (size_t)b * 8 * 1024 + spi;
#pragma unroll
    for (int ch = 0; ch < 8; ch++) {
        const u64 m = __ballot(lds[wid][ch][t] > 0.5f);
        if (t == 0) ob[(size_t)ch * 1024] = m;
    }
}

// ---------------- conv2 (8->32) bits in, FLOAT out, fused CUBA --------------
__global__ __launch_bounds__(256) void conv2_cuba(const u64* __restrict__ s1b,
                                                  const float* __restrict__ w2T,
                                                  float* __restrict__ s2) {
    __shared__ float lds[4][16][68];
    const int wid = RFL(threadIdx.x >> 6), t = threadIdx.x & 63;
    const int task = RFL(blockIdx.x) * 4 + wid;  // 0..2047
    const int og = task & 1;
    const int spi = (task >> 1) & 63;
    const int b = task >> 7;
    const int oy = spi >> 3, ox = spi & 7;

    float a[16];
#pragma unroll
    for (int j = 0; j < 16; j++) a[j] = 0.f;
    const u64* sb = s1b + (size_t)b * 8 * 1024;

    if (oy >= 1 && ox >= 1) {
        const u64* si = sb + (size_t)(oy * 4 - 1) * 32 + (ox * 4 - 1);
        for (int ci = 0; ci < 8; ci++) {
            u64 m[25];
#pragma unroll
            for (int ky = 0; ky < 5; ky++)
#pragma unroll
                for (int kx = 0; kx < 5; kx++)
                    m[ky * 5 + kx] = si[ci * 1024 + ky * 32 + kx];
#pragma unroll
            for (int k = 0; k < 25; k++) {
                const float xvk = bit2f(m[k], t);
                const float4* wp = (const float4*)(w2T + (ci * 25 + k) * 32 + og * 16);
                const float4 w0 = wp[0], w1 = wp[1], w2 = wp[2], w3 = wp[3];
                a[0]  = fmaf(w0.x, xvk, a[0]);  a[1]  = fmaf(w0.y, xvk, a[1]);
                a[2]  = fmaf(w0.z, xvk, a[2]);  a[3]  = fmaf(w0.w, xvk, a[3]);
                a[4]  = fmaf(w1.x, xvk, a[4]);  a[5]  = fmaf(w1.y, xvk, a[5]);
                a[6]  = fmaf(w1.z, xvk, a[6]);  a[7]  = fmaf(w1.w, xvk, a[7]);
                a[8]  = fmaf(w2.x, xvk, a[8]);  a[9]  = fmaf(w2.y, xvk, a[9]);
                a[10] = fmaf(w2.z, xvk, a[10]); a[11] = fmaf(w2.w, xvk, a[11]);
                a[12] = fmaf(w3.x, xvk, a[12]); a[13] = fmaf(w3.y, xvk, a[13]);
                a[14] = fmaf(w3.z, xvk, a[14]); a[15] = fmaf(w3.w, xvk, a[15]);
            }
        }
    } else {
        for (int ci = 0; ci < 8; ci++) {
#pragma unroll
            for (int ky = 0; ky < 5; ky++) {
                const int iy = oy * 4 + ky - 1;
                if (iy < 0 || iy >= 32) continue;
#pragma unroll
                for (int kx = 0; kx < 5; kx++) {
                    const int ix = ox * 4 + kx - 1;
                    if (ix < 0 || ix >= 32) continue;
                    const float xvk = bit2f(sb[ci * 1024 + iy * 32 + ix], t);
                    const float4* wp =
                        (const float4*)(w2T + (ci * 25 + ky * 5 + kx) * 32 + og * 16);
                    const float4 w0 = wp[0], w1 = wp[1], w2 = wp[2], w3 = wp[3];
                    a[0]  = fmaf(w0.x, xvk, a[0]);  a[1]  = fmaf(w0.y, xvk, a[1]);
                    a[2]  = fmaf(w0.z, xvk, a[2]);  a[3]  = fmaf(w0.w, xvk, a[3]);
                    a[4]  = fmaf(w1.x, xvk, a[4]);  a[5]  = fmaf(w1.y, xvk, a[5]);
                    a[6]  = fmaf(w1.z, xvk, a[6]);  a[7]  = fmaf(w1.w, xvk, a[7]);
                    a[8]  = fmaf(w2.x, xvk, a[8]);  a[9]  = fmaf(w2.y, xvk, a[9]);
                    a[10] = fmaf(w2.z, xvk, a[10]); a[11] = fmaf(w2.w, xvk, a[11]);
                    a[12] = fmaf(w3.x, xvk, a[12]); a[13] = fmaf(w3.y, xvk, a[13]);
                    a[14] = fmaf(w3.z, xvk, a[14]); a[15] = fmaf(w3.w, xvk, a[15]);
                }
            }
        }
    }
#pragma unroll
    for (int j = 0; j < 16; j++) lds[wid][j][t] = a[j];
    __syncthreads();
    if (t < 16) {
        const float* row = &lds[wid][t][0];
        float4* op = (float4*)(s2 + (((size_t)b * 32 + og * 16 + t) * 64 + spi) * TT);
        float c = 0.f, v = 0.f;
        for (int tc = 0; tc < 4; tc++) {
            float4 r0 = *(const float4*)&row[tc * 16 + 0];
            float4 r1 = *(const float4*)&row[tc * 16 + 4];
            float4 r2 = *(const float4*)&row[tc * 16 + 8];
            float4 r3 = *(const float4*)&row[tc * 16 + 12];
            scan4(c, v, r0); scan4(c, v, r1); scan4(c, v, r2); scan4(c, v, r3);
            op[tc * 4 + 0] = r0; op[tc * 4 + 1] = r1;
            op[tc * 4 + 2] = r2; op[tc * 4 + 3] = r3;
        }
    }
}

// ---------------- conv3 (32->64) float in/out, fused CUBA -------------------
template <int OY, int OX>
__device__ __forceinline__ void conv3_acc(const float* __restrict__ xb,
                                          const float* __restrict__ wTo,
                                          int wid, float* __restrict__ acc) {
    constexpr int KY0 = (OY == 0) ? 1 : 0;
    constexpr int KX0 = (OX == 0) ? 1 : 0;
    constexpr int NKY = 5 - KY0;
    constexpr int NKX = 5 - KX0;
    for (int c8 = 0; c8 < 8; c8++) {
        const int ci = wid * 8 + c8;
        float xv[NKY * NKX];
#pragma unroll
        for (int ky = KY0; ky < 5; ky++) {
#pragma unroll
            for (int kx = KX0; kx < 5; kx++) {
                const int iy = OY * 4 + ky - 1;
                const int ix = OX * 4 + kx - 1;
                xv[(ky - KY0) * NKX + (kx - KX0)] =
                    xb[((size_t)((ci * 8 + iy) * 8 + ix)) * TT];
            }
        }
#pragma unroll
        for (int ky = KY0; ky < 5; ky++) {
#pragma unroll
            for (int kx = KX0; kx < 5; kx++) {
                const float xvk = xv[(ky - KY0) * NKX + (kx - KX0)];
                const float4* wp = (const float4*)(wTo + (ci * 25 + ky * 5 + kx) * 64);
                const float4 wA = wp[0], wB = wp[1];
                acc[0] = fmaf(wA.x, xvk, acc[0]); acc[1] = fmaf(wA.y, xvk, acc[1]);
                acc[2] = fmaf(wA.z, xvk, acc[2]); acc[3] = fmaf(wA.w, xvk, acc[3]);
                acc[4] = fmaf(wB.x, xvk, acc[4]); acc[5] = fmaf(wB.y, xvk, acc[5]);
                acc[6] = fmaf(wB.z, xvk, acc[6]); acc[7] = fmaf(wB.w, xvk, acc[7]);
            }
        }
    }
}

__global__ __launch_bounds__(256) void conv3_cuba(const float* __restrict__ s2,
                                                  const float* __restrict__ wT,
                                                  float* __restrict__ s3) {
    __shared__ float red[4][8][68];
    const int wid = RFL(threadIdx.x >> 6), t = threadIdx.x & 63;
    const int og = RFL(blockIdx.x) & 7;
    const int spi = (RFL(blockIdx.x) >> 3) & 3;
    const int b = RFL(blockIdx.x) >> 5;

    float acc[8];
#pragma unroll
    for (int j = 0; j < 8; j++) acc[j] = 0.f;
    const float* xb = s2 + (size_t)b * 32 * 8 * 8 * TT + t;
    const float* wTo = wT + og * 8;

    switch (spi) {
        case 0: conv3_acc<0, 0>(xb, wTo, wid, acc); break;
        case 1: conv3_acc<0, 1>(xb, wTo, wid, acc); break;
        case 2: conv3_acc<1, 0>(xb, wTo, wid, acc); break;
        default: conv3_acc<1, 1>(xb, wTo, wid, acc); break;
    }
#pragma unroll
    for (int j = 0; j < 8; j++) red[wid][j][t] = acc[j];
    __syncthreads();
    if (wid == 0) {
#pragma unroll
        for (int j = 0; j < 8; j++)
            red[0][j][t] = ((red[0][j][t] + red[1][j][t]) + red[2][j][t]) + red[3][j][t];
    }
    __syncthreads();
    if (threadIdx.x < 8) {
        const int j = threadIdx.x;
        const float* row = &red[0][j][0];
        float4* op = (float4*)(s3 + ((size_t)b * 256 + og * 32 + j * 4 + spi) * TT);
        float c = 0.f, v = 0.f;
        for (int tc = 0; tc < 4; tc++) {
            float4 r0 = *(const float4*)&row[tc * 16 + 0];
            float4 r1 = *(const float4*)&row[tc * 16 + 4];
            float4 r2 = *(const float4*)&row[tc * 16 + 8];
            float4 r3 = *(const float4*)&row[tc * 16 + 12];
            scan4(c, v, r0); scan4(c, v, r1); scan4(c, v, r2); scan4(c, v, r3);
            op[tc * 4 + 0] = r0; op[tc * 4 + 1] = r1;
            op[tc * 4 + 2] = r2; op[tc * 4 + 3] = r3;
        }
    }
}

// ---------------- dense1 (256 -> 2056) float in/out, fused CUBA -------------
__global__ __launch_bounds__(256) void dense1_cuba(const float* __restrict__ s3,
                                                   const float* __restrict__ w,
                                                   float* __restrict__ s4) {
    __shared__ float lds[4][8][68];
    const int wid = threadIdx.x >> 6, t = threadIdx.x & 63;
    const int task = blockIdx.x * 4 + wid;  // 0..4111  (16 b x 257 og)
    const int bq = task / 257;
    const int ogq = task - bq * 257;
    const int b = RFL(bq);
    const int o0 = RFL(ogq * 8);

    float a0=0,a1=0,a2=0,a3=0,a4=0,a5=0,a6=0,a7=0;
    const float* ab = s3 + (size_t)b * 256 * TT + t;
    const float* r0 = w + (size_t)(o0 + 0) * 256;
    const float* r1 = w + (size_t)(o0 + 1) * 256;
    const float* r2 = w + (size_t)(o0 + 2) * 256;
    const float* r3 = w + (size_t)(o0 + 3) * 256;
    const float* r4 = w + (size_t)(o0 + 4) * 256;
    const float* r5 = w + (size_t)(o0 + 5) * 256;
    const float* r6 = w + (size_t)(o0 + 6) * 256;
    const float* r7 = w + (size_t)(o0 + 7) * 256;

#pragma unroll 2
    for (int i = 0; i < 256; i += 4) {
        const float av0 = ab[(size_t)(i + 0) * TT];
        const float av1 = ab[(size_t)(i + 1) * TT];
        const float av2 = ab[(size_t)(i + 2) * TT];
        const float av3 = ab[(size_t)(i + 3) * TT];
        const float4 q0 = *(const float4*)(r0 + i);
        const float4 q1 = *(const float4*)(r1 + i);
        const float4 q2 = *(const float4*)(r2 + i);
        const float4 q3 = *(const float4*)(r3 + i);
        const float4 q4 = *(const float4*)(r4 + i);
        const float4 q5 = *(const float4*)(r5 + i);
        const float4 q6 = *(const float4*)(r6 + i);
        const float4 q7 = *(const float4*)(r7 + i);
        a0 = fmaf(q0.x, av0, a0); a1 = fmaf(q1.x, av0, a1);
        a2 = fmaf(q2.x, av0, a2); a3 = fmaf(q3.x, av0, a3);
        a4 = fmaf(q4.x, av0, a4); a5 = fmaf(q5.x, av0, a5);
        a6 = fmaf(q6.x, av0, a6); a7 = fmaf(q7.x, av0, a7);
        a0 = fmaf(q0.y, av1, a0); a1 = fmaf(q1.y, av1, a1);
        a2 = fmaf(q2.y, av1, a2); a3 = fmaf(q3.y, av1, a3);
        a4 = fmaf(q4.y, av1, a4); a5 = fmaf(q5.y, av1, a5);
        a6 = fmaf(q6.y, av1, a6); a7 = fmaf(q7.y, av1, a7);
        a0 = fmaf(q0.z, av2, a0); a1 = fmaf(q1.z, av2, a1);
        a2 = fmaf(q2.z, av2, a2); a3 = fmaf(q3.z, av2, a3);
        a4 = fmaf(q4.z, av2, a4); a5 = fmaf(q5.z, av2, a5);
        a6 = fmaf(q6.z, av2, a6); a7 = fmaf(q7.z, av2, a7);
        a0 = fmaf(q0.w, av3, a0); a1 = fmaf(q1.w, av3, a1);
        a2 = fmaf(q2.w, av3, a2); a3 = fmaf(q3.w, av3, a3);
        a4 = fmaf(q4.w, av3, a4); a5 = fmaf(q5.w, av3, a5);
        a6 = fmaf(q6.w, av3, a6); a7 = fmaf(q7.w, av3, a7);
    }
    lds[wid][0][t] = a0; lds[wid][1][t] = a1; lds[wid][2][t] = a2; lds[wid][3][t] = a3;
    lds[wid][4][t] = a4; lds[wid][5][t] = a5; lds[wid][6][t] = a6; lds[wid][7][t] = a7;
    __syncthreads();
    if (t < 8) {
        const float* row = &lds[wid][t][0];
        float4* op = (float4*)(s4 + ((size_t)b * 2056 + o0 + t) * TT);
        float c = 0.f, v = 0.f;
        for (int tc = 0; tc < 4; tc++) {
            float4 r0q = *(const float4*)&row[tc * 16 + 0];
            float4 r1q = *(const float4*)&row[tc * 16 + 4];
            float4 r2q = *(const float4*)&row[tc * 16 + 8];
            float4 r3q = *(const float4*)&row[tc * 16 + 12];
            scan4(c, v, r0q); scan4(c, v, r1q); scan4(c, v, r2q); scan4(c, v, r3q);
            op[tc * 4 + 0] = r0q; op[tc * 4 + 1] = r1q;
            op[tc * 4 + 2] = r2q; op[tc * 4 + 3] = r3q;
        }
    }
}

// ---------------- dense2 stage 1: split-K partial sums (16 splits) ----------
// grid (16 sp, 16 b) = 256 blocks (1/CU). Split sp covers i in [sp*129,
// min(sp*129+129, 2056)); wave w takes i = i0+w, i0+w+4, ... Stage 2 sums the
// 16 partials in fixed sp order.
__global__ __launch_bounds__(256) void dense2_part(const float* __restrict__ s4,
                                                   const float* __restrict__ wP,
                                                   float* __restrict__ z4p) {
    __shared__ float red[4][11][64];
    const int sp = blockIdx.x, b = blockIdx.y;
    const int w = threadIdx.x >> 6, t = threadIdx.x & 63;
    const int i0 = sp * 129;
    const int iend = (i0 + 129 < 2056) ? i0 + 129 : 2056;
    const float* src = s4 + (size_t)b * 2056 * TT + t;

    float acc[11];
#pragma unroll
    for (int j = 0; j < 11; j++) acc[j] = 0.f;

#pragma unroll 4
    for (int i = i0 + w; i < iend; i += 4) {
        const float xv = src[(size_t)i * TT];
        const float4* wp = (const float4*)(wP + (size_t)i * 12);
        const float4 w0 = wp[0], w1 = wp[1], w2 = wp[2];
        acc[0]  = fmaf(w0.x, xv, acc[0]);  acc[1]  = fmaf(w0.y, xv, acc[1]);
        acc[2]  = fmaf(w0.z, xv, acc[2]);  acc[3]  = fmaf(w0.w, xv, acc[3]);
        acc[4]  = fmaf(w1.x, xv, acc[4]);  acc[5]  = fmaf(w1.y, xv, acc[5]);
        acc[6]  = fmaf(w1.z, xv, acc[6]);  acc[7]  = fmaf(w1.w, xv, acc[7]);
        acc[8]  = fmaf(w2.x, xv, acc[8]);  acc[9]  = fmaf(w2.y, xv, acc[9]);
        acc[10] = fmaf(w2.z, xv, acc[10]);
    }
#pragma unroll
    for (int j = 0; j < 11; j++) red[w][j][t] = acc[j];
    __syncthreads();
    if (w == 0) {
#pragma unroll
        for (int j = 0; j < 11; j++) {
            const float s = red[0][j][t] + red[1][j][t] + red[2][j][t] + red[3][j][t];
            z4p[(((size_t)b * 16 + sp) * 11 + j) * TT + t] = s;
        }
    }
}

// ---------------- dense2 stage 2: fixed-order reduce + final CUBA scan ------
__global__ __launch_bounds__(256) void dense2_scan(const float* __restrict__ z4p,
                                                   float* __restrict__ out) {
    __shared__ float z[11][64];
    const int b = blockIdx.x;
    for (int idx = threadIdx.x; idx < 11 * 64; idx += 256) {
        const int o = idx >> 6, t = idx & 63;
        float s = 0.f;
#pragma unroll
        for (int sp = 0; sp < 16; sp++)
            s += z4p[(((size_t)b * 16 + sp) * 11 + o) * TT + t];
        z[o][t] = s;
    }
    __syncthreads();
    if (threadIdx.x < 11) {
        const int o = threadIdx.x;
        float c = 0.f, v = 0.f;
        float* op = out + ((size_t)b * 11 + o) * TT;
#pragma unroll
        for (int t = 0; t < TT; t++) {
            float zz = z[o][t];
            scanc(c, v, zz);
            op[t] = zz;
        }
    }
}

extern "C" void kernel_launch(void* const* d_in, const int* in_sizes, int n_in,
                              void* d_out, int out_size, void* d_ws, size_t ws_size,
                              hipStream_t stream) {
    const float* x   = (const float*)d_in[0];
    const float* c1v = (const float*)d_in[1];  const float* c1g = (const float*)d_in[2];
    const float* c2v = (const float*)d_in[3];  const float* c2g = (const float*)d_in[4];
    const float* c3v = (const float*)d_in[5];  const float* c3g = (const float*)d_in[6];
    const float* d1v = (const float*)d_in[7];  const float* d1g = (const float*)d_in[8];
    const float* d2v = (const float*)d_in[9];  const float* d2g = (const float*)d_in[10];

    float* ws = (float*)d_ws;
    // weight region
    float* w1T  = ws + 0;        // (50,8)     = 400
    float* w2T  = ws + 400;      // (200,32)   = 6400
    float* w3T  = ws + 6800;     // (800,64)   = 51200
    float* wd1  = ws + 58000;    // (2056,256) original layout = 526336
    float* wd2P = ws + 584336;   // (2056,12) padded = 24672
    // float activation regions
    float* A = ws + 609008;
    float* B = A + 8388608;
    float* s3  = A;              // dense-in spikes (b,256,t)
    float* s4  = A + 262144;     // dense1 spikes (b,2056,t)
    float* s2  = B;              // conv2 spikes (b,32,8,8,t)
    float* z4p = B + 2097152;    // dense2 partials (b,16,11,t) = 180224
    // bitmask regions (even float offsets -> 8B aligned)
    u64* xbits  = (u64*)(ws + 13191920);  // 524288 u64 = 4 MB
    u64* s1bits = (u64*)(ws + 14240496);  // 131072 u64 = 1 MB
    (void)ws_size; (void)in_sizes; (void)n_in; (void)out_size;

    // weight norms + x packing fused into one dispatch
    prep<<<dim3(2171 + 4096), dim3(256), 0, stream>>>(
        c1v, c1g, w1T, c2v, c2g, w2T, c3v, c3g, w3T, d1v, d1g, wd1,
        d2v, d2g, wd2P, x, xbits);

    conv1_cuba <<<dim3(4096),   dim3(256), 0, stream>>>(xbits, w1T, s1bits);
    conv2_cuba <<<dim3(512),    dim3(256), 0, stream>>>(s1bits, w2T, s2);
    conv3_cuba <<<dim3(512),    dim3(256), 0, stream>>>(s2, w3T, s3);
    dense1_cuba<<<dim3(1028),   dim3(256), 0, stream>>>(s3, wd1, s4);
    dense2_part<<<dim3(16, 16), dim3(256), 0, stream>>>(s4, wd2P, z4p);
    dense2_scan<<<dim3(16),     dim3(256), 0, stream>>>(z4p, (float*)d_out);
}